// Round 8
// baseline (429.509 us; speedup 1.0000x reference)
//
#include <hip/hip_runtime.h>

#define BB 64
#define PP 8732
#define CC 81
#define RPW 8                     // rows per unit (chunk)
#define WSLOTS ((RPW * CC) / 4)   // 162 float4 slots per tensor tile
#define WRAW (RPW * CC)           // 648 floats per tensor tile
// per-wave LDS floats: rawT(648) + rawS(648) + psum(162) + spill(8) = 1466 -> 1468
#define WSTRIDE 1468
#define WPB 4                     // waves per block
#define NBLK 1536                 // persistent blocks: 6/CU * 256 CU
#define NWAVES (NBLK * WPB)       // 6144
#define WPBATCH (NWAVES / BB)     // 96 waves per batch
#define NCH ((PP + RPW - 1) / RPW) // 1092 chunks per batch (last has 4 rows)

// ---------- helpers ----------

__device__ __forceinline__ float sl1(float d) {
    d = fabsf(d);
    return d < 1.0f ? 0.5f * d * d : d - 0.5f;
}

// Direct global->LDS stage, no destination VGPR. LDS dest = wave-uniform base,
// HW appends lane*16 (proven absmax=0 in rounds 5-6).
__device__ __forceinline__ void glds16(const void* g, void* l) {
    __builtin_amdgcn_global_load_lds(
        (const __attribute__((address_space(1))) void*)g,
        (__attribute__((address_space(3))) void*)l, 16, 0, 0);
}

// Stage nslots float4s: full 64-lane steps + one exec-masked remainder step.
__device__ __forceinline__ void stageTile(const float4* __restrict__ g4,
                                          float* ldsBase, int nslots, int lane) {
    int full = nslots >> 6;
    for (int k = 0; k < full; ++k)
        glds16(g4 + (k << 6) + lane, ldsBase + (k << 8));
    int rem = nslots - (full << 6);
    if (lane < rem)
        glds16(g4 + (full << 6) + lane, ldsBase + (full << 8));
}

// Block reduce (blockDim.x multiple of 64, <=1024). Returns total to ALL threads.
__device__ __forceinline__ float blockReduceF(float v, volatile float* sb) {
    for (int off = 32; off; off >>= 1) v += __shfl_xor(v, off, 64);
    __syncthreads();
    if ((threadIdx.x & 63) == 0) sb[threadIdx.x >> 6] = v;
    __syncthreads();
    float r = 0.0f;
    int nw = blockDim.x >> 6;
    for (int i = 0; i < nw; ++i) r += sb[i];
    return r;
}

__device__ __forceinline__ int blockReduceI(int v, volatile int* sb) {
    for (int off = 32; off; off >>= 1) v += __shfl_xor(v, off, 64);
    __syncthreads();
    if ((threadIdx.x & 63) == 0) sb[threadIdx.x >> 6] = v;
    __syncthreads();
    int r = 0;
    int nw = blockDim.x >> 6;
    for (int i = 0; i < nw; ++i) r += sb[i];
    return r;
}

// ---------- kernel 0: zero accumulators ----------
__global__ void kInit(float* acc, int* numpos, int* ctr, float* locPart) {
    int t = threadIdx.x;
    if (t < 4) acc[t] = 0.0f;
    if (t < BB) { numpos[t] = 0; locPart[t] = 0.0f; locPart[BB + t] = 0.0f; }
    if (t == 0) ctr[0] = 0;
}

// ---------- per-slot softmax-denominator piece (R6-proven, unchanged) ----------
__device__ __forceinline__ void processSlot(int i, float4 v,
                                            float* psum, float* spill) {
    int f = i << 2;
    int r0 = f / 81;                         // compiler magic-mul
    int rem = f - r0 * 81;
    float e0 = __expf(v.x), e1 = __expf(v.y), e2 = __expf(v.z), e3 = __expf(v.w);
    float t01 = e0 + e1;
    float tot = t01 + e2 + e3;
    float ps = tot;
    if (rem >= 78) {                         // slot crosses into row r0+1
        int ns = 81 - rem;                   // elems belonging to r0: 1..3
        float a = (ns == 1) ? e0 : ((ns == 2) ? t01 : t01 + e2);
        ps = a;
        spill[r0 + 1] = tot - a;
    }
    psum[i] = ps;
}

// Wave-level row reduce + store (R6-proven, unchanged). 4 lanes per row.
__device__ __forceinline__ void waveReduceStore(float* __restrict__ dst,
                                                size_t rowBase, int nr, int lane,
                                                const float* psum,
                                                const float* spill,
                                                float gtv, int g_) {
    int r = lane >> 2, h = lane & 3;
    float gv = __shfl(gtv, r, 64);
    int   gr = __shfl(g_,  r, 64);
    if (r < nr) {
        int i0 = (81 * r + 3) >> 2;
        int i1 = (81 * (r + 1) + 3) >> 2;    // exclusive
        float s = (h == 0 && (r & 3)) ? spill[r] : 0.0f;
        for (int i = i0 + h; i < i1; i += 4) s += psum[i];
        s += __shfl_xor(s, 1, 64);
        s += __shfl_xor(s, 2, 64);
        if (h == 0) {
            float lc = __logf(s) - gv;
            dst[rowBase + r] = (gr > 0) ? -(lc + 1.0f) : lc;
        }
    }
}

// ---------- kStream: PERSISTENT waves running the R6-proven unit schedule ----
// v8 (recovering from v7's NaN): v7 changed schedule + unit shape + structure
// at once and broke; this version changes ONLY the grid shape. 1536 blocks
// (6/CU, all resident, zero turnover after launch); wave W owns batch W&63
// and chunks (W>>6) + k*96 -- same batch for all its units, so loc partials
// accumulate in registers and the atomic triple fires once per wave.
// Per unit, the schedule is R6 VERBATIM (absmax=0 proven): conft + 3 T-glds +
// 3 S-glds issued, vmcnt(3) [conft+T resident, S flying], T compute,
// vmcnt(0), S compute, conditional loc gathers. The per-unit vmcnt(3) stays
// correct in a loop because vmcnt counts from the NEWEST ops: leftover lc
// stores / loc gathers from the previous unit are older and simply drain
// early. Buffer-reuse WAR is closed by the existing lgkmcnt(0)s (every
// rawT/rawS read drains mid-unit) + same-wave LDS ordering.
__global__ __launch_bounds__(256, 6) void kStream(
        const float* __restrict__ confT, const float* __restrict__ confS,
        const int* __restrict__ conft,
        const float4* __restrict__ locT4, const float4* __restrict__ locS4,
        const float4* __restrict__ loct4,
        float* __restrict__ lcT, float* __restrict__ lcS,
        float* __restrict__ locPart, int* __restrict__ numpos) {
    __shared__ __align__(16) float lds[WPB * WSTRIDE];
    int tid = threadIdx.x;
    int w = tid >> 6, lane = tid & 63;
    float* rawT  = lds + w * WSTRIDE;        // 648 floats, 16B-aligned
    float* rawS  = rawT + WRAW;              // 648 floats
    float* psum  = rawS + WRAW;              // 162 floats
    float* spill = psum + WSLOTS;            // 8 floats

    int W = blockIdx.x * WPB + w;
    int b = W & 63;                          // wave's batch (fixed)
    int c0 = W >> 6;                         // first chunk (0..95)

    float sT = 0.0f, sS = 0.0f;
    int cnt = 0;

    for (int c = c0; c < NCH; c += WPBATCH) {
        int row0 = c * RPW;
        int nr = min(RPW, PP - row0);        // 8; 4 only at c == 1091
        size_t rowBase = (size_t)b * PP + row0;
        const float4* __restrict__ gT4 = (const float4*)(confT + rowBase * (size_t)CC);
        const float4* __restrict__ gS4 = (const float4*)(confS + rowBase * (size_t)CC);
        bool hasrow = lane < nr;
        int g_ = 0;

        if (nr == RPW) {
            // ---- R6 schedule, verbatim ----
            if (hasrow) g_ = conft[rowBase + lane];          // VMEM 1 (oldest)
            __builtin_amdgcn_sched_barrier(0);
            stageTile(gT4, rawT, WSLOTS, lane);              // VMEM 2-4
            __builtin_amdgcn_sched_barrier(0);
            stageTile(gS4, rawS, WSLOTS, lane);              // VMEM 5-7
            __builtin_amdgcn_sched_barrier(0);

            asm volatile("s_waitcnt vmcnt(3)" ::: "memory"); // conft+T resident
            __builtin_amdgcn_sched_barrier(0);
            float gtvT = hasrow ? rawT[lane * CC + g_] : 0.0f;
            const float4* rT4 = (const float4*)rawT;
            processSlot(lane,      rT4[lane],      psum, spill);
            processSlot(lane + 64, rT4[lane + 64], psum, spill);
            if (lane < WSLOTS - 128) processSlot(128 + lane, rT4[128 + lane], psum, spill);
            asm volatile("s_waitcnt lgkmcnt(0)" ::: "memory");
            __builtin_amdgcn_sched_barrier(0);
            waveReduceStore(lcT, rowBase, nr, lane, psum, spill, gtvT, g_);
            __builtin_amdgcn_sched_barrier(0);

            asm volatile("s_waitcnt vmcnt(0)" ::: "memory"); // S resident
            __builtin_amdgcn_sched_barrier(0);
            float gtvS = hasrow ? rawS[lane * CC + g_] : 0.0f;
            const float4* rS4 = (const float4*)rawS;
            processSlot(lane,      rS4[lane],      psum, spill);
            processSlot(lane + 64, rS4[lane + 64], psum, spill);
            if (lane < WSLOTS - 128) processSlot(128 + lane, rS4[128 + lane], psum, spill);
            asm volatile("s_waitcnt lgkmcnt(0)" ::: "memory");
            __builtin_amdgcn_sched_barrier(0);
            waveReduceStore(lcS, rowBase, nr, lane, psum, spill, gtvS, g_);
        } else {
            // tail chunk (nr == 4): stage both, full drain, compute.
            int nq4 = (nr * CC) >> 2;                        // 81 slots
            stageTile(gT4, rawT, nq4, lane);
            __builtin_amdgcn_sched_barrier(0);
            stageTile(gS4, rawS, nq4, lane);
            if (hasrow) g_ = conft[rowBase + lane];
            asm volatile("s_waitcnt vmcnt(0)" ::: "memory");
            __builtin_amdgcn_sched_barrier(0);
            float gtvT = hasrow ? rawT[lane * CC + g_] : 0.0f;
            float gtvS = hasrow ? rawS[lane * CC + g_] : 0.0f;
            const float4* rT4 = (const float4*)rawT;
            const float4* rS4 = (const float4*)rawS;
            for (int i = lane; i < nq4; i += 64) processSlot(i, rT4[i], psum, spill);
            asm volatile("s_waitcnt lgkmcnt(0)" ::: "memory");
            __builtin_amdgcn_sched_barrier(0);
            waveReduceStore(lcT, rowBase, nr, lane, psum, spill, gtvT, g_);
            __builtin_amdgcn_sched_barrier(0);
            for (int i = lane; i < nq4; i += 64) processSlot(i, rS4[i], psum, spill);
            asm volatile("s_waitcnt lgkmcnt(0)" ::: "memory");
            __builtin_amdgcn_sched_barrier(0);
            waveReduceStore(lcS, rowBase, nr, lane, psum, spill, gtvS, g_);
        }

        // ---- fused loc work (~2% of rows), accumulated in registers ----
        if (hasrow && g_ > 0) {
            size_t idx = rowBase + lane;
            float4 gt = loct4[idx];
            float4 aT = locT4[idx];
            float4 aS = locS4[idx];
            sT += sl1(aT.x - gt.x) + sl1(aT.y - gt.y) + sl1(aT.z - gt.z) + sl1(aT.w - gt.w);
            sS += sl1(aS.x - gt.x) + sl1(aS.y - gt.y) + sl1(aS.z - gt.z) + sl1(aS.w - gt.w);
            cnt += 1;
        }
    }

    // One reduce + atomic triple per wave (b is wave-uniform).
    for (int off = 32; off; off >>= 1) {
        sT  += __shfl_xor(sT,  off, 64);
        sS  += __shfl_xor(sS,  off, 64);
        cnt += __shfl_xor(cnt, off, 64);
    }
    if (lane == 0 && cnt) {
        atomicAdd(&locPart[b], sT);
        atomicAdd(&locPart[BB + b], sS);
        atomicAdd(&numpos[b], cnt);
    }
}

// ---------- kernel C: hard-negative mining (radix select) + fused finalize ----------
// Unchanged from round 6 (absmax=0). grid = (2, BB).
#define WROT(w, bin) (((w) << 8) | (((bin) + (w) * 17) & 0xFF))
__global__ __launch_bounds__(1024) void kC(const float* __restrict__ lcT,
                                           const float* __restrict__ lcS,
                                           const int* __restrict__ numpos,
                                           const float* __restrict__ locPart,
                                           float* acc, int* ctr,
                                           float* __restrict__ out) {
    __shared__ unsigned keys[PP];
    __shared__ int whist[16 * 256];
    __shared__ int hist[256];
    __shared__ float fsb[16];
    __shared__ int isb[16];
    __shared__ int selBin, selAbove, lastFlag, wsum[4];
    int b = blockIdx.y;
    int tid = threadIdx.x;
    int lane = tid & 63;
    const float* src = ((blockIdx.x == 0) ? lcT : lcS) + (size_t)b * PP;

    float posSum = 0.0f;
    for (int i = tid; i < PP; i += 1024) {
        float v = src[i];
        keys[i] = (v < 0.0f) ? 0u : __float_as_uint(v);
        if (v < 0.0f) posSum += (-v - 1.0f);
    }
    posSum = blockReduceF(posSum, fsb);   // internal syncs fence keys[] writes

    int np = numpos[b];
    int k = min(3 * np, PP - 1);
    float mined = 0.0f;
    if (k > 0) {
        unsigned prefix = 0;
        int kk = k;
        int wid = tid >> 6;
        for (int round = 0; round < 4; ++round) {
            int shift = 24 - 8 * round;
            for (int i = tid; i < 16 * 256; i += 1024) whist[i] = 0;
            __syncthreads();
            for (int i = tid; i < PP; i += 1024) {
                unsigned key = keys[i];
                bool match = (round == 0) || ((key >> (shift + 8)) == prefix);
                if (match) atomicAdd(&whist[WROT(wid, (key >> shift) & 0xFF)], 1);
            }
            __syncthreads();
            if (tid < 256) {
                int h2 = 0;
                #pragma unroll
                for (int w = 0; w < 16; ++w) h2 += whist[WROT(w, tid)];
                hist[tid] = h2;
            }
            __syncthreads();
            // inclusive suffix scan of hist[256]: wave shuffle scan, 2 barriers.
            int x = (tid < 256) ? hist[tid] : 0;
            for (int d = 1; d < 64; d <<= 1) {
                int y = __shfl_down(x, d, 64);
                if (lane + d < 64) x += y;
            }
            if (tid < 256 && lane == 0) wsum[tid >> 6] = x;
            __syncthreads();
            if (tid < 256) {
                int wv = tid >> 6;
                int add = 0;
                if (wv < 3) add += wsum[wv + 1];
                if (wv < 2) add += wsum[wv + 2];
                if (wv < 1) add += wsum[wv + 3];
                int sfx = x + add;                 // sum_{j>=tid} hist[j]
                hist[tid] = sfx;
            }
            __syncthreads();
            if (tid < 256) {
                int above = (tid < 255) ? hist[tid + 1] : 0;
                if (above < kk && hist[tid] >= kk) {   // unique bin
                    selBin = tid;
                    selAbove = above;
                }
            }
            __syncthreads();
            prefix = (prefix << 8) | (unsigned)selBin;
            kk -= selAbove;
            __syncthreads();
        }
        // prefix = bit pattern of the exact k-th largest key
        int c = 0;
        float s = 0.0f;
        for (int i = tid; i < PP; i += 1024) {
            unsigned key = keys[i];
            if (key > prefix) { c += 1; s += __uint_as_float(key); }
        }
        c = blockReduceI(c, isb);
        s = blockReduceF(s, fsb);
        mined = s + (float)(k - c) * __uint_as_float(prefix);
    }
    if (tid == 0) {
        atomicAdd(&acc[(blockIdx.x == 0) ? 2 : 3], posSum + mined);
        __threadfence();                       // our acc write visible before ctr
        int old = atomicAdd(ctr, 1);           // device-scope
        lastFlag = (old == 2 * BB - 1) ? 1 : 0;
    }
    __syncthreads();
    if (lastFlag) {                            // fused finalize: last block
        __threadfence();
        int v = 0;
        float pT = 0.0f, pS = 0.0f;
        if (tid < BB) {
            v  = __hip_atomic_load(&numpos[tid], __ATOMIC_RELAXED, __HIP_MEMORY_SCOPE_AGENT);
            pT = __hip_atomic_load(&locPart[tid], __ATOMIC_RELAXED, __HIP_MEMORY_SCOPE_AGENT);
            pS = __hip_atomic_load(&locPart[BB + tid], __ATOMIC_RELAXED, __HIP_MEMORY_SCOPE_AGENT);
        }
        if (tid < 64) {
            for (int off = 32; off; off >>= 1) {
                v  += __shfl_xor(v,  off, 64);
                pT += __shfl_xor(pT, off, 64);
                pS += __shfl_xor(pS, off, 64);
            }
        }
        if (tid == 0) {
            float N = (float)v;
            float a2 = __hip_atomic_load(&acc[2], __ATOMIC_RELAXED, __HIP_MEMORY_SCOPE_AGENT);
            float a3 = __hip_atomic_load(&acc[3], __ATOMIC_RELAXED, __HIP_MEMORY_SCOPE_AGENT);
            out[0] = pT / N;  // loss_lT / N
            out[1] = a2 / N;  // loss_cT / N
            out[2] = pS / N;  // loss_lS / N
            out[3] = a3 / N;  // loss_cS / N
        }
    }
}

// ---------- launch ----------
extern "C" void kernel_launch(void* const* d_in, const int* in_sizes, int n_in,
                              void* d_out, int out_size, void* d_ws, size_t ws_size,
                              hipStream_t stream) {
    const float* locT  = (const float*)d_in[0];
    const float* confT = (const float*)d_in[1];
    const float* locS  = (const float*)d_in[2];
    const float* confS = (const float*)d_in[3];
    const float* loct  = (const float*)d_in[4];
    const int*   conft = (const int*)d_in[5];
    float* out = (float*)d_out;

    float* lcT = (float*)d_ws;
    float* lcS = lcT + (size_t)BB * PP;
    float* acc = lcS + (size_t)BB * PP;
    int* numpos = (int*)(acc + 4);
    int* ctr = numpos + BB;
    float* locPart = (float*)(ctr + 1);

    kInit<<<1, 64, 0, stream>>>(acc, numpos, ctr, locPart);

    kStream<<<NBLK, 256, 0, stream>>>(confT, confS, conft,
                                      (const float4*)locT, (const float4*)locS,
                                      (const float4*)loct, lcT, lcS,
                                      locPart, numpos);

    dim3 gC(2, BB);
    kC<<<gC, 1024, 0, stream>>>(lcT, lcS, numpos, locPart, acc, ctr, out);
}